// Round 1
// baseline (2083.428 us; speedup 1.0000x reference)
//
#include <hip/hip_runtime.h>

#define PD 64

// ---------------- CSR build ----------------
__global__ void k_deg(const int* __restrict__ ei, const float* __restrict__ w,
                      int* deg_in, int* deg_out, float* sw_in, float* sw_out, int E) {
  int e = blockIdx.x * blockDim.x + threadIdx.x;
  if (e >= E) return;
  int s = ei[e], d = ei[E + e];
  atomicAdd(&deg_in[d], 1);
  atomicAdd(&deg_out[s], 1);
  float we = w[e];
  atomicAdd(&sw_in[d], we);
  atomicAdd(&sw_out[s], we);
}

__global__ void k_scan1(const int* __restrict__ deg, int* rowp, int* csum, int n) {
  __shared__ int sh[256];
  int tid = threadIdx.x;
  int i = blockIdx.x * 256 + tid;
  int v = (i < n) ? deg[i] : 0;
  sh[tid] = v; __syncthreads();
  for (int off = 1; off < 256; off <<= 1) {
    int t = (tid >= off) ? sh[tid - off] : 0;
    __syncthreads();
    sh[tid] += t;
    __syncthreads();
  }
  if (i < n) rowp[i] = sh[tid] - v;          // exclusive within chunk
  if (tid == 255) csum[blockIdx.x] = sh[255]; // chunk total
}

__global__ void k_scan2(int* csum, int n) {
  __shared__ int sh[512];
  int tid = threadIdx.x;
  int v = (tid < n) ? csum[tid] : 0;
  sh[tid] = v; __syncthreads();
  for (int off = 1; off < 512; off <<= 1) {
    int t = (tid >= off) ? sh[tid - off] : 0;
    __syncthreads();
    sh[tid] += t;
    __syncthreads();
  }
  if (tid < n) csum[tid] = sh[tid] - v;      // exclusive chunk offsets
}

__global__ void k_scan3(int* rowp, int* pos, const int* __restrict__ csum, int n, int total) {
  int i = blockIdx.x * 256 + threadIdx.x;
  if (i < n) {
    int r = rowp[i] + csum[blockIdx.x];
    rowp[i] = r;
    pos[i] = r;
  }
  if (i == 0) rowp[n] = total;
}

__global__ void k_fill(const int* __restrict__ ei, int* pos_in, int* pos_out,
                       int* col_in, int* col_out, int E) {
  int e = blockIdx.x * blockDim.x + threadIdx.x;
  if (e >= E) return;
  int s = ei[e], d = ei[E + e];
  int p = atomicAdd(&pos_in[d], 1);
  col_in[p] = s;
  int q = atomicAdd(&pos_out[s], 1);
  col_out[q] = d;
}

// ---------------- per-step weight folding ----------------
// c1[t][p] = sum_k Wc1[t][p][k]     * W1[t][k]
// c3[t][p] = sum_k Wc1[t][p][128+k] * v3[k],  v3 = W3[t] @ relu(W4[t])
// Mt[t][j][p] = sum_k Wc1[t][p][64+k] * W2[t][k][j]   (j-major for conflict-free reads)
// Wc2t[t][j][p] = Wc2[t][p][j] ; WcompT[j][p] = Wcomp[p][j] ; W7t[j][k] = W7[k][j]
__global__ void k_wprep(const float* __restrict__ W1, const float* __restrict__ W2,
                        const float* __restrict__ W3, const float* __restrict__ W4,
                        const float* __restrict__ Wc1, const float* __restrict__ Wc2,
                        const float* __restrict__ Wcomp, const float* __restrict__ W7,
                        float* c1, float* c3, float* Mt, float* Wc2t,
                        float* WcompT, float* W7t) {
  int t = blockIdx.x;
  int tid = threadIdx.x;
  __shared__ float r4[64], v3[64];
  if (tid < 64) r4[tid] = fmaxf(W4[t * 64 + tid], 0.f);
  __syncthreads();
  if (tid < 64) {
    float s = 0.f;
    for (int k = 0; k < 64; ++k) s += W3[t * 4096 + tid * 64 + k] * r4[k];
    v3[tid] = s;
    float s1 = 0.f;
    for (int k = 0; k < 64; ++k) s1 += Wc1[t * 12288 + tid * 192 + k] * W1[t * 64 + k];
    c1[t * 64 + tid] = s1;
  }
  __syncthreads();
  if (tid < 64) {
    float s = 0.f;
    for (int k = 0; k < 64; ++k) s += Wc1[t * 12288 + tid * 192 + 128 + k] * v3[k];
    c3[t * 64 + tid] = s;
  }
  for (int idx = tid; idx < 4096; idx += 256) {
    int j = idx >> 6, p = idx & 63;
    float s = 0.f;
    for (int k = 0; k < 64; ++k)
      s += Wc1[t * 12288 + p * 192 + 64 + k] * W2[t * 4096 + k * 64 + j];
    Mt[t * 4096 + idx] = s;
    Wc2t[t * 4096 + idx] = Wc2[t * 4096 + p * 64 + j];
  }
  if (t == 0) {
    for (int idx = tid; idx < 8192; idx += 256) {
      int j = idx >> 6, p = idx & 63;
      WcompT[idx] = Wcomp[p * 128 + j];
    }
    for (int idx = tid; idx < 4096; idx += 256) {
      int j = idx >> 6, p = idx & 63;
      W7t[idx] = W7[p * 64 + j];
    }
  }
}

// ---------------- edge aggregation (gather over CSR) ----------------
__global__ __launch_bounds__(256) void k_agg(
    const int* __restrict__ row_in, const int* __restrict__ col_in,
    const int* __restrict__ row_out, const int* __restrict__ col_out,
    const float* __restrict__ mu, float* __restrict__ agg_in,
    float* __restrict__ agg_out, int n) {
  int wave = (blockIdx.x * blockDim.x + threadIdx.x) >> 6;
  int lane = threadIdx.x & 63;
  if (wave >= n) return;
  float acc = 0.f;
  int b = row_in[wave], e = row_in[wave + 1];
  for (int k = b; k < e; ++k) acc += mu[(size_t)col_in[k] * 64 + lane];
  agg_in[(size_t)wave * 64 + lane] = acc;
  acc = 0.f;
  b = row_out[wave]; e = row_out[wave + 1];
  for (int k = b; k < e; ++k) acc += mu[(size_t)col_out[k] * 64 + lane];
  agg_out[(size_t)wave * 64 + lane] = acc;
}

// ---------------- fused per-node GEMM chain ----------------
// per node: z_dir = relu(x*c1 + sw_dir*c3 + agg_dir @ Mt)
//           m_dir = relu(z_dir @ Wc2t)
//           mu    = relu([m_in, m_out] @ WcompT)
// wave handles 4 nodes (lane = output feature p), float4 LDS broadcasts carry
// the 4 nodes' operand values; weights staged in LDS (72.5 KB -> 2 blocks/CU).
__global__ __launch_bounds__(256, 2) void k_node(
    const float* __restrict__ x, const float* __restrict__ sw_in,
    const float* __restrict__ sw_out, const float* __restrict__ agg_in,
    const float* __restrict__ agg_out, const float* __restrict__ c1g,
    const float* __restrict__ c3g, const float* __restrict__ Mtg,
    const float* __restrict__ Wc2tg, const float* __restrict__ WcompTg,
    float* __restrict__ mu, int n, int t, int haveAgg) {
  __shared__ float sM[4096], sC2[4096], sCmp[8192];
  __shared__ float sc1[64], sc3[64];
  __shared__ float4 S4[4][128];
  int tid = threadIdx.x;
  for (int i = tid; i < 4096; i += 256) {
    sM[i] = Mtg[t * 4096 + i];
    sC2[i] = Wc2tg[t * 4096 + i];
  }
  for (int i = tid; i < 8192; i += 256) sCmp[i] = WcompTg[i];
  if (tid < 64) { sc1[tid] = c1g[t * 64 + tid]; sc3[tid] = c3g[t * 64 + tid]; }
  __syncthreads();
  int lane = tid & 63, w = tid >> 6;
  float4* S = S4[w];
  int ngroups = (n + 15) >> 4;

  for (int g0 = blockIdx.x; g0 < ngroups; g0 += gridDim.x) {
    int node0 = (g0 * 4 + w) * 4;
    float m_in[4], m_out[4];
#pragma unroll
    for (int dir = 0; dir < 2; ++dir) {
      const float* agg = dir ? agg_out : agg_in;
      const float* sw = dir ? sw_out : sw_in;
      float acc[4];
#pragma unroll
      for (int i = 0; i < 4; ++i) {
        int nd = node0 + i;
        float xv = (nd < n) ? x[nd] : 0.f;
        float sv = (nd < n) ? sw[nd] : 0.f;
        acc[i] = xv * sc1[lane] + sv * sc3[lane];
      }
      if (haveAgg) {
        float a0 = (node0 + 0 < n) ? agg[(size_t)(node0 + 0) * 64 + lane] : 0.f;
        float a1 = (node0 + 1 < n) ? agg[(size_t)(node0 + 1) * 64 + lane] : 0.f;
        float a2 = (node0 + 2 < n) ? agg[(size_t)(node0 + 2) * 64 + lane] : 0.f;
        float a3 = (node0 + 3 < n) ? agg[(size_t)(node0 + 3) * 64 + lane] : 0.f;
        S[lane] = make_float4(a0, a1, a2, a3);
        __builtin_amdgcn_wave_barrier();
#pragma unroll 8
        for (int j = 0; j < 64; ++j) {
          float mw = sM[j * 64 + lane];
          float4 a = S[j];
          acc[0] = fmaf(a.x, mw, acc[0]);
          acc[1] = fmaf(a.y, mw, acc[1]);
          acc[2] = fmaf(a.z, mw, acc[2]);
          acc[3] = fmaf(a.w, mw, acc[3]);
        }
        __builtin_amdgcn_wave_barrier();
      }
#pragma unroll
      for (int i = 0; i < 4; ++i) acc[i] = fmaxf(acc[i], 0.f);
      S[lane] = make_float4(acc[0], acc[1], acc[2], acc[3]);
      __builtin_amdgcn_wave_barrier();
      float m[4] = {0.f, 0.f, 0.f, 0.f};
#pragma unroll 8
      for (int j = 0; j < 64; ++j) {
        float mw = sC2[j * 64 + lane];
        float4 a = S[j];
        m[0] = fmaf(a.x, mw, m[0]);
        m[1] = fmaf(a.y, mw, m[1]);
        m[2] = fmaf(a.z, mw, m[2]);
        m[3] = fmaf(a.w, mw, m[3]);
      }
      __builtin_amdgcn_wave_barrier();
      if (dir == 0) {
#pragma unroll
        for (int i = 0; i < 4; ++i) m_in[i] = fmaxf(m[i], 0.f);
      } else {
#pragma unroll
        for (int i = 0; i < 4; ++i) m_out[i] = fmaxf(m[i], 0.f);
      }
    }
    S[lane] = make_float4(m_in[0], m_in[1], m_in[2], m_in[3]);
    S[64 + lane] = make_float4(m_out[0], m_out[1], m_out[2], m_out[3]);
    __builtin_amdgcn_wave_barrier();
    float o[4] = {0.f, 0.f, 0.f, 0.f};
#pragma unroll 8
    for (int j = 0; j < 128; ++j) {
      float mw = sCmp[j * 64 + lane];
      float4 a = S[j];
      o[0] = fmaf(a.x, mw, o[0]);
      o[1] = fmaf(a.y, mw, o[1]);
      o[2] = fmaf(a.z, mw, o[2]);
      o[3] = fmaf(a.w, mw, o[3]);
    }
    __builtin_amdgcn_wave_barrier();
#pragma unroll
    for (int i = 0; i < 4; ++i) {
      int nd = node0 + i;
      if (nd < n) mu[(size_t)nd * 64 + lane] = fmaxf(o[i], 0.f);
    }
  }
}

// ---------------- pooling (batch_ids sorted -> chunked partial sums) ----------------
__global__ __launch_bounds__(256) void k_pool(
    const float* __restrict__ mu, const int* __restrict__ batch,
    float* __restrict__ pool, int n) {
  int gw = (blockIdx.x * blockDim.x + threadIdx.x) >> 6;
  int lane = threadIdx.x & 63;
  int start = gw * 256;
  if (start >= n) return;
  int end = min(start + 256, n);
  int cur = batch[start];
  float acc = 0.f;
  for (int i = start; i < end; ++i) {
    int b = batch[i];
    if (b != cur) {
      atomicAdd(&pool[cur * 64 + lane], acc);
      acc = 0.f;
      cur = b;
    }
    acc += mu[(size_t)i * 64 + lane];
  }
  atomicAdd(&pool[cur * 64 + lane], acc);
}

__global__ void k_poolw6(const float* __restrict__ pool, const float* __restrict__ W6,
                         float* __restrict__ out) {
  int idx = blockIdx.x * blockDim.x + threadIdx.x;  // < 4096
  int g = idx >> 6, p = idx & 63;
  float s = 0.f;
  for (int k = 0; k < 64; ++k) s += pool[g * 64 + k] * W6[p * 64 + k];
  out[idx] = s;
}

// ---------------- head: out[n] = relu(W5 . [relu(poolW6[b]), relu(mu@W7.T)]) ----------------
__global__ __launch_bounds__(256) void k_final(
    const float* __restrict__ mu, const int* __restrict__ batch,
    const float* __restrict__ poolw6, const float* __restrict__ W7t,
    const float* __restrict__ W5, float* __restrict__ out, int n) {
  __shared__ float S[4][64];
  int tid = threadIdx.x, lane = tid & 63, w = tid >> 6;
  int node = blockIdx.x * 4 + w;
  if (node >= n) return;
  float mv = mu[(size_t)node * 64 + lane];
  S[w][lane] = mv;
  __builtin_amdgcn_wave_barrier();
  int g = batch[node];
  float t1 = fmaxf(poolw6[g * 64 + lane], 0.f);
  float acc = 0.f;
#pragma unroll 8
  for (int j = 0; j < 64; ++j) acc = fmaf(S[w][j], W7t[j * 64 + lane], acc);
  float t2 = fmaxf(acc, 0.f);
  float val = W5[lane] * t1 + W5[64 + lane] * t2;
  for (int off = 32; off > 0; off >>= 1) val += __shfl_down(val, off);
  if (lane == 0) out[node] = fmaxf(val, 0.f);
}

extern "C" void kernel_launch(void* const* d_in, const int* in_sizes, int n_in,
                              void* d_out, int out_size, void* d_ws, size_t ws_size,
                              hipStream_t stream) {
  const float* x = (const float*)d_in[0];
  const float* weight = (const float*)d_in[1];
  const int* ei = (const int*)d_in[2];
  const int* batch = (const int*)d_in[3];
  const float* W1 = (const float*)d_in[4];
  const float* W2 = (const float*)d_in[5];
  const float* W3 = (const float*)d_in[6];
  const float* W4 = (const float*)d_in[7];
  const float* Wc1 = (const float*)d_in[8];
  const float* Wc2 = (const float*)d_in[9];
  const float* Wcomp = (const float*)d_in[10];
  const float* W5 = (const float*)d_in[11];
  const float* W6 = (const float*)d_in[12];
  const float* W7 = (const float*)d_in[13];
  float* out = (float*)d_out;
  int N = in_sizes[0];
  int E = in_sizes[1];
  int T = in_sizes[4] / 64;

  char* ws = (char*)d_ws;
  size_t off = 0;
  auto alloc = [&](size_t bytes) {
    size_t o = off;
    off += (bytes + 255) & ~(size_t)255;
    return o;
  };
  // zeroed region (one memset)
  size_t o_deg_in = alloc((size_t)N * 4);
  size_t o_deg_out = alloc((size_t)N * 4);
  size_t o_sw_in = alloc((size_t)N * 4);
  size_t o_sw_out = alloc((size_t)N * 4);
  size_t o_pool = alloc(4096 * 4);
  size_t zero_end = off;
  size_t o_row_in = alloc((size_t)(N + 1) * 4);
  size_t o_row_out = alloc((size_t)(N + 1) * 4);
  size_t o_pos_in = alloc((size_t)N * 4);
  size_t o_pos_out = alloc((size_t)N * 4);
  size_t o_col_in = alloc((size_t)E * 4);
  size_t o_col_out = alloc((size_t)E * 4);
  size_t o_csum = alloc(512 * 4);
  size_t o_mu = alloc((size_t)N * 64 * 4);
  size_t o_agg_in = alloc((size_t)N * 64 * 4);
  size_t o_agg_out = alloc((size_t)N * 64 * 4);
  size_t o_c1 = alloc(4 * 64 * 4);
  size_t o_c3 = alloc(4 * 64 * 4);
  size_t o_Mt = alloc(4 * 4096 * 4);
  size_t o_Wc2t = alloc(4 * 4096 * 4);
  size_t o_WcompT = alloc(8192 * 4);
  size_t o_W7t = alloc(4096 * 4);
  size_t o_poolw6 = alloc(4096 * 4);
  (void)ws_size; (void)n_in; (void)out_size;

  hipMemsetAsync(ws, 0, zero_end, stream);

  int gE = (E + 255) / 256;
  k_deg<<<gE, 256, 0, stream>>>(ei, weight, (int*)(ws + o_deg_in), (int*)(ws + o_deg_out),
                                (float*)(ws + o_sw_in), (float*)(ws + o_sw_out), E);
  int nch = (N + 255) / 256;
  k_scan1<<<nch, 256, 0, stream>>>((int*)(ws + o_deg_in), (int*)(ws + o_row_in),
                                   (int*)(ws + o_csum), N);
  k_scan2<<<1, 512, 0, stream>>>((int*)(ws + o_csum), nch);
  k_scan3<<<nch, 256, 0, stream>>>((int*)(ws + o_row_in), (int*)(ws + o_pos_in),
                                   (int*)(ws + o_csum), N, E);
  k_scan1<<<nch, 256, 0, stream>>>((int*)(ws + o_deg_out), (int*)(ws + o_row_out),
                                   (int*)(ws + o_csum), N);
  k_scan2<<<1, 512, 0, stream>>>((int*)(ws + o_csum), nch);
  k_scan3<<<nch, 256, 0, stream>>>((int*)(ws + o_row_out), (int*)(ws + o_pos_out),
                                   (int*)(ws + o_csum), N, E);
  k_fill<<<gE, 256, 0, stream>>>(ei, (int*)(ws + o_pos_in), (int*)(ws + o_pos_out),
                                 (int*)(ws + o_col_in), (int*)(ws + o_col_out), E);
  k_wprep<<<T, 256, 0, stream>>>(W1, W2, W3, W4, Wc1, Wc2, Wcomp, W7,
                                 (float*)(ws + o_c1), (float*)(ws + o_c3),
                                 (float*)(ws + o_Mt), (float*)(ws + o_Wc2t),
                                 (float*)(ws + o_WcompT), (float*)(ws + o_W7t));

  int gN16 = (N + 15) / 16;
  int gN4 = (N + 3) / 4;
  int gNode = gN16 < 2048 ? gN16 : 2048;
  for (int t = 0; t < T; ++t) {
    if (t > 0)
      k_agg<<<gN4, 256, 0, stream>>>((int*)(ws + o_row_in), (int*)(ws + o_col_in),
                                     (int*)(ws + o_row_out), (int*)(ws + o_col_out),
                                     (float*)(ws + o_mu), (float*)(ws + o_agg_in),
                                     (float*)(ws + o_agg_out), N);
    k_node<<<gNode, 256, 0, stream>>>(x, (float*)(ws + o_sw_in), (float*)(ws + o_sw_out),
                                      (float*)(ws + o_agg_in), (float*)(ws + o_agg_out),
                                      (float*)(ws + o_c1), (float*)(ws + o_c3),
                                      (float*)(ws + o_Mt), (float*)(ws + o_Wc2t),
                                      (float*)(ws + o_WcompT), (float*)(ws + o_mu),
                                      N, t, t > 0 ? 1 : 0);
  }
  int gPool = ((N + 255) / 256 + 3) / 4;
  k_pool<<<gPool, 256, 0, stream>>>((float*)(ws + o_mu), batch, (float*)(ws + o_pool), N);
  k_poolw6<<<16, 256, 0, stream>>>((float*)(ws + o_pool), W6, (float*)(ws + o_poolw6));
  k_final<<<gN4, 256, 0, stream>>>((float*)(ws + o_mu), batch, (float*)(ws + o_poolw6),
                                   (float*)(ws + o_W7t), W5, out, N);
}

// Round 2
// 1576.178 us; speedup vs baseline: 1.3218x; 1.3218x over previous
//
#include <hip/hip_runtime.h>

#define PD 64

// ---------------- CSR build ----------------
__global__ void k_deg(const int* __restrict__ ei, const float* __restrict__ w,
                      int* deg_in, int* deg_out, float* sw_in, float* sw_out, int E) {
  int e = blockIdx.x * blockDim.x + threadIdx.x;
  if (e >= E) return;
  int s = ei[e], d = ei[E + e];
  atomicAdd(&deg_in[d], 1);
  atomicAdd(&deg_out[s], 1);
  float we = w[e];
  atomicAdd(&sw_in[d], we);
  atomicAdd(&sw_out[s], we);
}

// scans handle BOTH deg arrays via blockIdx.y (0=in, 1=out); csum segmented by 512
__global__ void k_scan1(const int* __restrict__ degA, const int* __restrict__ degB,
                        int* rowpA, int* rowpB, int* csum, int n) {
  const int* deg = blockIdx.y ? degB : degA;
  int* rowp = blockIdx.y ? rowpB : rowpA;
  int* cs = csum + blockIdx.y * 512;
  __shared__ int sh[256];
  int tid = threadIdx.x;
  int i = blockIdx.x * 256 + tid;
  int v = (i < n) ? deg[i] : 0;
  sh[tid] = v; __syncthreads();
  for (int off = 1; off < 256; off <<= 1) {
    int t = (tid >= off) ? sh[tid - off] : 0;
    __syncthreads();
    sh[tid] += t;
    __syncthreads();
  }
  if (i < n) rowp[i] = sh[tid] - v;          // exclusive within chunk
  if (tid == 255) cs[blockIdx.x] = sh[255];  // chunk total
}

__global__ void k_scan2(int* csum, int n) {
  int* cs = csum + blockIdx.x * 512;
  __shared__ int sh[512];
  int tid = threadIdx.x;
  int v = (tid < n) ? cs[tid] : 0;
  sh[tid] = v; __syncthreads();
  for (int off = 1; off < 512; off <<= 1) {
    int t = (tid >= off) ? sh[tid - off] : 0;
    __syncthreads();
    sh[tid] += t;
    __syncthreads();
  }
  if (tid < n) cs[tid] = sh[tid] - v;        // exclusive chunk offsets
}

__global__ void k_scan3(int* rowpA, int* rowpB, int* posA, int* posB,
                        const int* __restrict__ csum, int n, int total) {
  int* rowp = blockIdx.y ? rowpB : rowpA;
  int* pos = blockIdx.y ? posB : posA;
  const int* cs = csum + blockIdx.y * 512;
  int i = blockIdx.x * 256 + threadIdx.x;
  if (i < n) {
    int r = rowp[i] + cs[blockIdx.x];
    rowp[i] = r;
    pos[i] = r;
  }
  if (i == 0) rowp[n] = total;
}

__global__ void k_fill(const int* __restrict__ ei, int* pos_in, int* pos_out,
                       int* col_in, int* col_out, int E) {
  int e = blockIdx.x * blockDim.x + threadIdx.x;
  if (e >= E) return;
  int s = ei[e], d = ei[E + e];
  int p = atomicAdd(&pos_in[d], 1);
  col_in[p] = s;
  int q = atomicAdd(&pos_out[s], 1);
  col_out[q] = d;
}

// ---------------- per-step weight folding ----------------
__global__ void k_wprep(const float* __restrict__ W1, const float* __restrict__ W2,
                        const float* __restrict__ W3, const float* __restrict__ W4,
                        const float* __restrict__ Wc1, const float* __restrict__ Wc2,
                        const float* __restrict__ Wcomp, const float* __restrict__ W7,
                        float* c1, float* c3, float* Mt, float* Wc2t,
                        float* WcompT, float* W7t) {
  int t = blockIdx.x;
  int tid = threadIdx.x;
  __shared__ float r4[64], v3[64];
  if (tid < 64) r4[tid] = fmaxf(W4[t * 64 + tid], 0.f);
  __syncthreads();
  if (tid < 64) {
    float s = 0.f;
    for (int k = 0; k < 64; ++k) s += W3[t * 4096 + tid * 64 + k] * r4[k];
    v3[tid] = s;
    float s1 = 0.f;
    for (int k = 0; k < 64; ++k) s1 += Wc1[t * 12288 + tid * 192 + k] * W1[t * 64 + k];
    c1[t * 64 + tid] = s1;
  }
  __syncthreads();
  if (tid < 64) {
    float s = 0.f;
    for (int k = 0; k < 64; ++k) s += Wc1[t * 12288 + tid * 192 + 128 + k] * v3[k];
    c3[t * 64 + tid] = s;
  }
  for (int idx = tid; idx < 4096; idx += 256) {
    int j = idx >> 6, p = idx & 63;
    float s = 0.f;
    for (int k = 0; k < 64; ++k)
      s += Wc1[t * 12288 + p * 192 + 64 + k] * W2[t * 4096 + k * 64 + j];
    Mt[t * 4096 + idx] = s;
    Wc2t[t * 4096 + idx] = Wc2[t * 4096 + p * 64 + j];
  }
  if (t == 0) {
    for (int idx = tid; idx < 8192; idx += 256) {
      int j = idx >> 6, p = idx & 63;
      WcompT[idx] = Wcomp[p * 128 + j];
    }
    for (int idx = tid; idx < 4096; idx += 256) {
      int j = idx >> 6, p = idx & 63;
      W7t[idx] = W7[p * 64 + j];
    }
  }
}

// ---------------- edge aggregation (gather over CSR, ILP=8) ----------------
__global__ __launch_bounds__(256) void k_agg(
    const int* __restrict__ row_in, const int* __restrict__ col_in,
    const int* __restrict__ row_out, const int* __restrict__ col_out,
    const float* __restrict__ mu, float* __restrict__ agg_in,
    float* __restrict__ agg_out, int n) {
  int wave = (blockIdx.x * blockDim.x + threadIdx.x) >> 6;
  int lane = threadIdx.x & 63;
  if (wave >= n) return;
#pragma unroll
  for (int dir = 0; dir < 2; ++dir) {
    const int* __restrict__ row = dir ? row_out : row_in;
    const int* __restrict__ col = dir ? col_out : col_in;
    float* __restrict__ agg = dir ? agg_out : agg_in;
    int b = row[wave], e = row[wave + 1];
    float a0 = 0.f, a1 = 0.f, a2 = 0.f, a3 = 0.f;
    if (b < e) {
      int last = e - 1;
      for (int k = b; k < e; k += 8) {
        int idx[8];
        float msk[8];
#pragma unroll
        for (int i = 0; i < 8; ++i) {
          int kk = k + i;
          idx[i] = col[kk <= last ? kk : last];   // clamped, wave-uniform
          msk[i] = (kk <= last) ? 1.f : 0.f;
        }
        float v[8];
#pragma unroll
        for (int i = 0; i < 8; ++i)
          v[i] = mu[(size_t)idx[i] * 64 + lane];  // 8 independent row loads
        a0 = fmaf(msk[0], v[0], a0);
        a1 = fmaf(msk[1], v[1], a1);
        a2 = fmaf(msk[2], v[2], a2);
        a3 = fmaf(msk[3], v[3], a3);
        a0 = fmaf(msk[4], v[4], a0);
        a1 = fmaf(msk[5], v[5], a1);
        a2 = fmaf(msk[6], v[6], a2);
        a3 = fmaf(msk[7], v[7], a3);
      }
    }
    agg[(size_t)wave * 64 + lane] = (a0 + a1) + (a2 + a3);
  }
}

// ---------------- fused per-node GEMM chain ----------------
__global__ __launch_bounds__(256, 2) void k_node(
    const float* __restrict__ x, const float* __restrict__ sw_in,
    const float* __restrict__ sw_out, const float* __restrict__ agg_in,
    const float* __restrict__ agg_out, const float* __restrict__ c1g,
    const float* __restrict__ c3g, const float* __restrict__ Mtg,
    const float* __restrict__ Wc2tg, const float* __restrict__ WcompTg,
    float* __restrict__ mu, int n, int t, int haveAgg) {
  __shared__ float sM[4096], sC2[4096], sCmp[8192];
  __shared__ float sc1[64], sc3[64];
  __shared__ float4 S4[4][128];
  int tid = threadIdx.x;
  for (int i = tid; i < 4096; i += 256) {
    sM[i] = Mtg[t * 4096 + i];
    sC2[i] = Wc2tg[t * 4096 + i];
  }
  for (int i = tid; i < 8192; i += 256) sCmp[i] = WcompTg[i];
  if (tid < 64) { sc1[tid] = c1g[t * 64 + tid]; sc3[tid] = c3g[t * 64 + tid]; }
  __syncthreads();
  int lane = tid & 63, w = tid >> 6;
  float4* S = S4[w];
  int ngroups = (n + 15) >> 4;

  for (int g0 = blockIdx.x; g0 < ngroups; g0 += gridDim.x) {
    int node0 = (g0 * 4 + w) * 4;
    float m_in[4], m_out[4];
#pragma unroll
    for (int dir = 0; dir < 2; ++dir) {
      const float* agg = dir ? agg_out : agg_in;
      const float* sw = dir ? sw_out : sw_in;
      float acc[4];
#pragma unroll
      for (int i = 0; i < 4; ++i) {
        int nd = node0 + i;
        float xv = (nd < n) ? x[nd] : 0.f;
        float sv = (nd < n) ? sw[nd] : 0.f;
        acc[i] = xv * sc1[lane] + sv * sc3[lane];
      }
      if (haveAgg) {
        float a0 = (node0 + 0 < n) ? agg[(size_t)(node0 + 0) * 64 + lane] : 0.f;
        float a1 = (node0 + 1 < n) ? agg[(size_t)(node0 + 1) * 64 + lane] : 0.f;
        float a2 = (node0 + 2 < n) ? agg[(size_t)(node0 + 2) * 64 + lane] : 0.f;
        float a3 = (node0 + 3 < n) ? agg[(size_t)(node0 + 3) * 64 + lane] : 0.f;
        S[lane] = make_float4(a0, a1, a2, a3);
        __builtin_amdgcn_wave_barrier();
#pragma unroll 8
        for (int j = 0; j < 64; ++j) {
          float mw = sM[j * 64 + lane];
          float4 a = S[j];
          acc[0] = fmaf(a.x, mw, acc[0]);
          acc[1] = fmaf(a.y, mw, acc[1]);
          acc[2] = fmaf(a.z, mw, acc[2]);
          acc[3] = fmaf(a.w, mw, acc[3]);
        }
        __builtin_amdgcn_wave_barrier();
      }
#pragma unroll
      for (int i = 0; i < 4; ++i) acc[i] = fmaxf(acc[i], 0.f);
      S[lane] = make_float4(acc[0], acc[1], acc[2], acc[3]);
      __builtin_amdgcn_wave_barrier();
      float m[4] = {0.f, 0.f, 0.f, 0.f};
#pragma unroll 8
      for (int j = 0; j < 64; ++j) {
        float mw = sC2[j * 64 + lane];
        float4 a = S[j];
        m[0] = fmaf(a.x, mw, m[0]);
        m[1] = fmaf(a.y, mw, m[1]);
        m[2] = fmaf(a.z, mw, m[2]);
        m[3] = fmaf(a.w, mw, m[3]);
      }
      __builtin_amdgcn_wave_barrier();
      if (dir == 0) {
#pragma unroll
        for (int i = 0; i < 4; ++i) m_in[i] = fmaxf(m[i], 0.f);
      } else {
#pragma unroll
        for (int i = 0; i < 4; ++i) m_out[i] = fmaxf(m[i], 0.f);
      }
    }
    S[lane] = make_float4(m_in[0], m_in[1], m_in[2], m_in[3]);
    S[64 + lane] = make_float4(m_out[0], m_out[1], m_out[2], m_out[3]);
    __builtin_amdgcn_wave_barrier();
    float o[4] = {0.f, 0.f, 0.f, 0.f};
#pragma unroll 8
    for (int j = 0; j < 128; ++j) {
      float mw = sCmp[j * 64 + lane];
      float4 a = S[j];
      o[0] = fmaf(a.x, mw, o[0]);
      o[1] = fmaf(a.y, mw, o[1]);
      o[2] = fmaf(a.z, mw, o[2]);
      o[3] = fmaf(a.w, mw, o[3]);
    }
    __builtin_amdgcn_wave_barrier();
#pragma unroll
    for (int i = 0; i < 4; ++i) {
      int nd = node0 + i;
      if (nd < n) mu[(size_t)nd * 64 + lane] = fmaxf(o[i], 0.f);
    }
  }
}

// ---------------- pooling (batch_ids sorted -> chunked partial sums) ----------------
__global__ __launch_bounds__(256) void k_pool(
    const float* __restrict__ mu, const int* __restrict__ batch,
    float* __restrict__ pool, int n) {
  int gw = (blockIdx.x * blockDim.x + threadIdx.x) >> 6;
  int lane = threadIdx.x & 63;
  int start = gw * 256;
  if (start >= n) return;
  int end = min(start + 256, n);
  int cur = batch[start];
  float acc = 0.f;
  for (int i = start; i < end; ++i) {
    int b = batch[i];
    if (b != cur) {
      atomicAdd(&pool[cur * 64 + lane], acc);
      acc = 0.f;
      cur = b;
    }
    acc += mu[(size_t)i * 64 + lane];
  }
  atomicAdd(&pool[cur * 64 + lane], acc);
}

__global__ void k_poolw6(const float* __restrict__ pool, const float* __restrict__ W6,
                         float* __restrict__ out) {
  int idx = blockIdx.x * blockDim.x + threadIdx.x;  // < 4096
  int g = idx >> 6, p = idx & 63;
  float s = 0.f;
  for (int k = 0; k < 64; ++k) s += pool[g * 64 + k] * W6[p * 64 + k];
  out[idx] = s;
}

// ---------------- head ----------------
__global__ __launch_bounds__(256) void k_final(
    const float* __restrict__ mu, const int* __restrict__ batch,
    const float* __restrict__ poolw6, const float* __restrict__ W7t,
    const float* __restrict__ W5, float* __restrict__ out, int n) {
  __shared__ float S[4][64];
  int tid = threadIdx.x, lane = tid & 63, w = tid >> 6;
  int node = blockIdx.x * 4 + w;
  if (node >= n) return;
  float mv = mu[(size_t)node * 64 + lane];
  S[w][lane] = mv;
  __builtin_amdgcn_wave_barrier();
  int g = batch[node];
  float t1 = fmaxf(poolw6[g * 64 + lane], 0.f);
  float acc = 0.f;
#pragma unroll 8
  for (int j = 0; j < 64; ++j) acc = fmaf(S[w][j], W7t[j * 64 + lane], acc);
  float t2 = fmaxf(acc, 0.f);
  float val = W5[lane] * t1 + W5[64 + lane] * t2;
  for (int off = 32; off > 0; off >>= 1) val += __shfl_down(val, off);
  if (lane == 0) out[node] = fmaxf(val, 0.f);
}

extern "C" void kernel_launch(void* const* d_in, const int* in_sizes, int n_in,
                              void* d_out, int out_size, void* d_ws, size_t ws_size,
                              hipStream_t stream) {
  const float* x = (const float*)d_in[0];
  const float* weight = (const float*)d_in[1];
  const int* ei = (const int*)d_in[2];
  const int* batch = (const int*)d_in[3];
  const float* W1 = (const float*)d_in[4];
  const float* W2 = (const float*)d_in[5];
  const float* W3 = (const float*)d_in[6];
  const float* W4 = (const float*)d_in[7];
  const float* Wc1 = (const float*)d_in[8];
  const float* Wc2 = (const float*)d_in[9];
  const float* Wcomp = (const float*)d_in[10];
  const float* W5 = (const float*)d_in[11];
  const float* W6 = (const float*)d_in[12];
  const float* W7 = (const float*)d_in[13];
  float* out = (float*)d_out;
  int N = in_sizes[0];
  int E = in_sizes[1];
  int T = in_sizes[4] / 64;

  char* ws = (char*)d_ws;
  size_t off = 0;
  auto alloc = [&](size_t bytes) {
    size_t o = off;
    off += (bytes + 255) & ~(size_t)255;
    return o;
  };
  // zeroed region (one memset)
  size_t o_deg_in = alloc((size_t)N * 4);
  size_t o_deg_out = alloc((size_t)N * 4);
  size_t o_sw_in = alloc((size_t)N * 4);
  size_t o_sw_out = alloc((size_t)N * 4);
  size_t o_pool = alloc(4096 * 4);
  size_t zero_end = off;
  size_t o_row_in = alloc((size_t)(N + 1) * 4);
  size_t o_row_out = alloc((size_t)(N + 1) * 4);
  size_t o_pos_in = alloc((size_t)N * 4);
  size_t o_pos_out = alloc((size_t)N * 4);
  size_t o_col_in = alloc((size_t)E * 4);
  size_t o_col_out = alloc((size_t)E * 4);
  size_t o_csum = alloc(1024 * 4);
  size_t o_mu = alloc((size_t)N * 64 * 4);
  size_t o_agg_in = alloc((size_t)N * 64 * 4);
  size_t o_agg_out = alloc((size_t)N * 64 * 4);
  size_t o_c1 = alloc(4 * 64 * 4);
  size_t o_c3 = alloc(4 * 64 * 4);
  size_t o_Mt = alloc(4 * 4096 * 4);
  size_t o_Wc2t = alloc(4 * 4096 * 4);
  size_t o_WcompT = alloc(8192 * 4);
  size_t o_W7t = alloc(4096 * 4);
  size_t o_poolw6 = alloc(4096 * 4);
  (void)ws_size; (void)n_in; (void)out_size;

  hipMemsetAsync(ws, 0, zero_end, stream);

  int gE = (E + 255) / 256;
  k_deg<<<gE, 256, 0, stream>>>(ei, weight, (int*)(ws + o_deg_in), (int*)(ws + o_deg_out),
                                (float*)(ws + o_sw_in), (float*)(ws + o_sw_out), E);
  int nch = (N + 255) / 256;
  dim3 g2(nch, 2);
  k_scan1<<<g2, 256, 0, stream>>>((int*)(ws + o_deg_in), (int*)(ws + o_deg_out),
                                  (int*)(ws + o_row_in), (int*)(ws + o_row_out),
                                  (int*)(ws + o_csum), N);
  k_scan2<<<2, 512, 0, stream>>>((int*)(ws + o_csum), nch);
  k_scan3<<<g2, 256, 0, stream>>>((int*)(ws + o_row_in), (int*)(ws + o_row_out),
                                  (int*)(ws + o_pos_in), (int*)(ws + o_pos_out),
                                  (int*)(ws + o_csum), N, E);
  k_fill<<<gE, 256, 0, stream>>>(ei, (int*)(ws + o_pos_in), (int*)(ws + o_pos_out),
                                 (int*)(ws + o_col_in), (int*)(ws + o_col_out), E);
  k_wprep<<<T, 256, 0, stream>>>(W1, W2, W3, W4, Wc1, Wc2, Wcomp, W7,
                                 (float*)(ws + o_c1), (float*)(ws + o_c3),
                                 (float*)(ws + o_Mt), (float*)(ws + o_Wc2t),
                                 (float*)(ws + o_WcompT), (float*)(ws + o_W7t));

  int gN16 = (N + 15) / 16;
  int gN4 = (N + 3) / 4;
  int gNode = gN16 < 2048 ? gN16 : 2048;
  for (int t = 0; t < T; ++t) {
    if (t > 0)
      k_agg<<<gN4, 256, 0, stream>>>((int*)(ws + o_row_in), (int*)(ws + o_col_in),
                                     (int*)(ws + o_row_out), (int*)(ws + o_col_out),
                                     (float*)(ws + o_mu), (float*)(ws + o_agg_in),
                                     (float*)(ws + o_agg_out), N);
    k_node<<<gNode, 256, 0, stream>>>(x, (float*)(ws + o_sw_in), (float*)(ws + o_sw_out),
                                      (float*)(ws + o_agg_in), (float*)(ws + o_agg_out),
                                      (float*)(ws + o_c1), (float*)(ws + o_c3),
                                      (float*)(ws + o_Mt), (float*)(ws + o_Wc2t),
                                      (float*)(ws + o_WcompT), (float*)(ws + o_mu),
                                      N, t, t > 0 ? 1 : 0);
  }
  int gPool = ((N + 255) / 256 + 3) / 4;
  k_pool<<<gPool, 256, 0, stream>>>((float*)(ws + o_mu), batch, (float*)(ws + o_pool), N);
  k_poolw6<<<16, 256, 0, stream>>>((float*)(ws + o_pool), W6, (float*)(ws + o_poolw6));
  k_final<<<gN4, 256, 0, stream>>>((float*)(ws + o_mu), batch, (float*)(ws + o_poolw6),
                                   (float*)(ws + o_W7t), W5, out, N);
}

// Round 3
// 1114.638 us; speedup vs baseline: 1.8692x; 1.4141x over previous
//
#include <hip/hip_runtime.h>

#define PD 64
#define BIN_C 6144   // edges staged per block in k_bin (48KB LDS)
#define RB 512       // nodes per bucket (log2 = 9)

// ---------------- phase 1: bin edges by bucket (locality-preserving) ----------------
// dir 0: bucket by dst, payload src (in-CSR). dir 1: bucket by src, payload dst.
// entry = uint2{ (neighbor<<9)|local , bits(w) }
__global__ __launch_bounds__(256) void k_bin(const int* __restrict__ ei,
    const float* __restrict__ w, uint2* __restrict__ bkt_in, uint2* __restrict__ bkt_out,
    int* __restrict__ bcnt, int E, int K, int cap) {
  __shared__ uint2 staged[BIN_C];
  __shared__ unsigned short bin16[BIN_C];
  __shared__ int cnt[256], base[257], off[256];
  int dir = blockIdx.y;
  const int* __restrict__ keys = dir ? ei : ei + E;
  const int* __restrict__ vals = dir ? ei + E : ei;
  uint2* __restrict__ bdst = dir ? bkt_out : bkt_in;
  int tid = threadIdx.x;
  int e0 = blockIdx.x * BIN_C;
  int count = min(BIN_C, E - e0);
  cnt[tid] = 0;
  __syncthreads();
  for (int i = tid; i < count; i += 256) {
    int b = keys[e0 + i] >> 9;
    bin16[i] = (unsigned short)b;
    atomicAdd(&cnt[b], 1);
  }
  __syncthreads();
  // exclusive scan of cnt -> base (scratch: off)
  int v = cnt[tid];
  off[tid] = v;
  __syncthreads();
  for (int o = 1; o < 256; o <<= 1) {
    int t = (tid >= o) ? off[tid - o] : 0;
    __syncthreads();
    off[tid] += t;
    __syncthreads();
  }
  base[tid] = off[tid] - v;
  if (tid == 255) base[256] = off[255];
  __syncthreads();
  off[tid] = 0;
  __syncthreads();
  // place bin-sorted into staged
  for (int i = tid; i < count; i += 256) {
    int e = e0 + i;
    int k = keys[e];
    int b = bin16[i];
    int l = k & (RB - 1);
    unsigned int packed = ((unsigned int)vals[e] << 9) | (unsigned int)l;
    int p = base[b] + atomicAdd(&off[b], 1);
    staged[p] = make_uint2(packed, __float_as_uint(w[e]));
  }
  __syncthreads();
  // reserve global bucket space: one atomic per (block,bucket)
  if (tid < K) {
    int c = cnt[tid];
    off[tid] = c > 0 ? atomicAdd(&bcnt[dir * K + tid], c) : 0;
  }
  __syncthreads();
  // flush: contiguous burst per bin
  for (int i = tid; i < count; i += 256) {
    int lo = 0, hi = K;
    while (hi - lo > 1) { int mid = (lo + hi) >> 1; if (base[mid] <= i) lo = mid; else hi = mid; }
    int b = lo;
    int rel = off[b] + (i - base[b]);
    if (rel < cap) bdst[(size_t)b * cap + rel] = staged[i];
  }
}

// ---------------- phase 2: per-bucket local CSR (LDS only, no global atomics) -------
__global__ __launch_bounds__(256) void k_bucket(
    const uint2* __restrict__ bkt_in, const uint2* __restrict__ bkt_out,
    const int* __restrict__ bcnt,
    int* __restrict__ beg_in, int* __restrict__ end_in,
    int* __restrict__ beg_out, int* __restrict__ end_out,
    float* __restrict__ sw_in, float* __restrict__ sw_out,
    int* __restrict__ col_in, int* __restrict__ col_out,
    int cap, int N, int K) {
  __shared__ int deg[RB], pos[RB], off[RB];
  __shared__ float swl[RB];
  __shared__ int ps[256];
  int b = blockIdx.x, dir = blockIdx.y, tid = threadIdx.x;
  const uint2* __restrict__ bkt = (dir ? bkt_out : bkt_in) + (size_t)b * cap;
  int* __restrict__ beg = dir ? beg_out : beg_in;
  int* __restrict__ end = dir ? end_out : end_in;
  float* __restrict__ swg = dir ? sw_out : sw_in;
  int* __restrict__ col = dir ? col_out : col_in;
  int len = bcnt[dir * K + b];
  if (len > cap) len = cap;
  deg[tid] = 0; deg[tid + 256] = 0;
  swl[tid] = 0.f; swl[tid + 256] = 0.f;
  __syncthreads();
  for (int i = tid; i < len; i += 256) {
    uint2 u = bkt[i];
    int l = u.x & (RB - 1);
    atomicAdd(&deg[l], 1);
    atomicAdd(&swl[l], __uint_as_float(u.y));
  }
  __syncthreads();
  // exclusive scan deg[0..512) with 256 threads (pair + HS)
  int a0 = deg[2 * tid], a1 = deg[2 * tid + 1];
  ps[tid] = a0 + a1;
  __syncthreads();
  for (int o = 1; o < 256; o <<= 1) {
    int t = (tid >= o) ? ps[tid - o] : 0;
    __syncthreads();
    ps[tid] += t;
    __syncthreads();
  }
  int ex = ps[tid] - (a0 + a1);
  pos[2 * tid] = ex;
  pos[2 * tid + 1] = ex + a0;
  off[tid] = 0; off[tid + 256] = 0;
  __syncthreads();
  int base_node = b << 9;
  size_t colbase = (size_t)b * cap;
  for (int l = tid; l < RB; l += 256) {
    int g = base_node + l;
    if (g < N) {
      beg[g] = (int)(colbase + pos[l]);
      end[g] = (int)(colbase + pos[l] + deg[l]);
      swg[g] = swl[l];
    }
  }
  __syncthreads();
  for (int i = tid; i < len; i += 256) {
    uint2 u = bkt[i];
    int l = u.x & (RB - 1);
    int s = (int)(u.x >> 9);
    int p = pos[l] + atomicAdd(&off[l], 1);
    col[colbase + p] = s;   // writes localized to this bucket's ~32KB region
  }
}

// ---------------- per-step weight folding ----------------
__global__ void k_wprep(const float* __restrict__ W1, const float* __restrict__ W2,
                        const float* __restrict__ W3, const float* __restrict__ W4,
                        const float* __restrict__ Wc1, const float* __restrict__ Wc2,
                        const float* __restrict__ Wcomp, const float* __restrict__ W7,
                        float* c1, float* c3, float* Mt, float* Wc2t,
                        float* WcompT, float* W7t) {
  int t = blockIdx.x;
  int tid = threadIdx.x;
  __shared__ float r4[64], v3[64];
  if (tid < 64) r4[tid] = fmaxf(W4[t * 64 + tid], 0.f);
  __syncthreads();
  if (tid < 64) {
    float s = 0.f;
    for (int k = 0; k < 64; ++k) s += W3[t * 4096 + tid * 64 + k] * r4[k];
    v3[tid] = s;
    float s1 = 0.f;
    for (int k = 0; k < 64; ++k) s1 += Wc1[t * 12288 + tid * 192 + k] * W1[t * 64 + k];
    c1[t * 64 + tid] = s1;
  }
  __syncthreads();
  if (tid < 64) {
    float s = 0.f;
    for (int k = 0; k < 64; ++k) s += Wc1[t * 12288 + tid * 192 + 128 + k] * v3[k];
    c3[t * 64 + tid] = s;
  }
  for (int idx = tid; idx < 4096; idx += 256) {
    int j = idx >> 6, p = idx & 63;
    float s = 0.f;
    for (int k = 0; k < 64; ++k)
      s += Wc1[t * 12288 + p * 192 + 64 + k] * W2[t * 4096 + k * 64 + j];
    Mt[t * 4096 + idx] = s;
    Wc2t[t * 4096 + idx] = Wc2[t * 4096 + p * 64 + j];
  }
  if (t == 0) {
    for (int idx = tid; idx < 8192; idx += 256) {
      int j = idx >> 6, p = idx & 63;
      WcompT[idx] = Wcomp[p * 128 + j];
    }
    for (int idx = tid; idx < 4096; idx += 256) {
      int j = idx >> 6, p = idx & 63;
      W7t[idx] = W7[p * 64 + j];
    }
  }
}

// ---------------- edge aggregation (gather over CSR, ILP=8) ----------------
__global__ __launch_bounds__(256) void k_agg(
    const int* __restrict__ beg_in, const int* __restrict__ end_in,
    const int* __restrict__ col_in,
    const int* __restrict__ beg_out, const int* __restrict__ end_out,
    const int* __restrict__ col_out,
    const float* __restrict__ mu, float* __restrict__ agg_in,
    float* __restrict__ agg_out, int n) {
  int wave = (blockIdx.x * blockDim.x + threadIdx.x) >> 6;
  int lane = threadIdx.x & 63;
  if (wave >= n) return;
#pragma unroll
  for (int dir = 0; dir < 2; ++dir) {
    const int* __restrict__ bega = dir ? beg_out : beg_in;
    const int* __restrict__ enda = dir ? end_out : end_in;
    const int* __restrict__ col = dir ? col_out : col_in;
    float* __restrict__ agg = dir ? agg_out : agg_in;
    int b = bega[wave], e = enda[wave];
    float a0 = 0.f, a1 = 0.f, a2 = 0.f, a3 = 0.f;
    if (b < e) {
      int last = e - 1;
      for (int k = b; k < e; k += 8) {
        int idx[8];
        float msk[8];
#pragma unroll
        for (int i = 0; i < 8; ++i) {
          int kk = k + i;
          idx[i] = col[kk <= last ? kk : last];   // clamped, wave-uniform
          msk[i] = (kk <= last) ? 1.f : 0.f;
        }
        float v[8];
#pragma unroll
        for (int i = 0; i < 8; ++i)
          v[i] = mu[(size_t)idx[i] * 64 + lane];  // 8 independent row loads
        a0 = fmaf(msk[0], v[0], a0);
        a1 = fmaf(msk[1], v[1], a1);
        a2 = fmaf(msk[2], v[2], a2);
        a3 = fmaf(msk[3], v[3], a3);
        a0 = fmaf(msk[4], v[4], a0);
        a1 = fmaf(msk[5], v[5], a1);
        a2 = fmaf(msk[6], v[6], a2);
        a3 = fmaf(msk[7], v[7], a3);
      }
    }
    agg[(size_t)wave * 64 + lane] = (a0 + a1) + (a2 + a3);
  }
}

// ---------------- fused per-node GEMM chain ----------------
__global__ __launch_bounds__(256, 2) void k_node(
    const float* __restrict__ x, const float* __restrict__ sw_in,
    const float* __restrict__ sw_out, const float* __restrict__ agg_in,
    const float* __restrict__ agg_out, const float* __restrict__ c1g,
    const float* __restrict__ c3g, const float* __restrict__ Mtg,
    const float* __restrict__ Wc2tg, const float* __restrict__ WcompTg,
    float* __restrict__ mu, int n, int t, int haveAgg) {
  __shared__ float sM[4096], sC2[4096], sCmp[8192];
  __shared__ float sc1[64], sc3[64];
  __shared__ float4 S4[4][128];
  int tid = threadIdx.x;
  for (int i = tid; i < 4096; i += 256) {
    sM[i] = Mtg[t * 4096 + i];
    sC2[i] = Wc2tg[t * 4096 + i];
  }
  for (int i = tid; i < 8192; i += 256) sCmp[i] = WcompTg[i];
  if (tid < 64) { sc1[tid] = c1g[t * 64 + tid]; sc3[tid] = c3g[t * 64 + tid]; }
  __syncthreads();
  int lane = tid & 63, w = tid >> 6;
  float4* S = S4[w];
  int ngroups = (n + 15) >> 4;

  for (int g0 = blockIdx.x; g0 < ngroups; g0 += gridDim.x) {
    int node0 = (g0 * 4 + w) * 4;
    float m_in[4], m_out[4];
#pragma unroll
    for (int dir = 0; dir < 2; ++dir) {
      const float* agg = dir ? agg_out : agg_in;
      const float* sw = dir ? sw_out : sw_in;
      float acc[4];
#pragma unroll
      for (int i = 0; i < 4; ++i) {
        int nd = node0 + i;
        float xv = (nd < n) ? x[nd] : 0.f;
        float sv = (nd < n) ? sw[nd] : 0.f;
        acc[i] = xv * sc1[lane] + sv * sc3[lane];
      }
      if (haveAgg) {
        float a0 = (node0 + 0 < n) ? agg[(size_t)(node0 + 0) * 64 + lane] : 0.f;
        float a1 = (node0 + 1 < n) ? agg[(size_t)(node0 + 1) * 64 + lane] : 0.f;
        float a2 = (node0 + 2 < n) ? agg[(size_t)(node0 + 2) * 64 + lane] : 0.f;
        float a3 = (node0 + 3 < n) ? agg[(size_t)(node0 + 3) * 64 + lane] : 0.f;
        S[lane] = make_float4(a0, a1, a2, a3);
        __builtin_amdgcn_wave_barrier();
#pragma unroll 8
        for (int j = 0; j < 64; ++j) {
          float mw = sM[j * 64 + lane];
          float4 a = S[j];
          acc[0] = fmaf(a.x, mw, acc[0]);
          acc[1] = fmaf(a.y, mw, acc[1]);
          acc[2] = fmaf(a.z, mw, acc[2]);
          acc[3] = fmaf(a.w, mw, acc[3]);
        }
        __builtin_amdgcn_wave_barrier();
      }
#pragma unroll
      for (int i = 0; i < 4; ++i) acc[i] = fmaxf(acc[i], 0.f);
      S[lane] = make_float4(acc[0], acc[1], acc[2], acc[3]);
      __builtin_amdgcn_wave_barrier();
      float m[4] = {0.f, 0.f, 0.f, 0.f};
#pragma unroll 8
      for (int j = 0; j < 64; ++j) {
        float mw = sC2[j * 64 + lane];
        float4 a = S[j];
        m[0] = fmaf(a.x, mw, m[0]);
        m[1] = fmaf(a.y, mw, m[1]);
        m[2] = fmaf(a.z, mw, m[2]);
        m[3] = fmaf(a.w, mw, m[3]);
      }
      __builtin_amdgcn_wave_barrier();
      if (dir == 0) {
#pragma unroll
        for (int i = 0; i < 4; ++i) m_in[i] = fmaxf(m[i], 0.f);
      } else {
#pragma unroll
        for (int i = 0; i < 4; ++i) m_out[i] = fmaxf(m[i], 0.f);
      }
    }
    S[lane] = make_float4(m_in[0], m_in[1], m_in[2], m_in[3]);
    S[64 + lane] = make_float4(m_out[0], m_out[1], m_out[2], m_out[3]);
    __builtin_amdgcn_wave_barrier();
    float o[4] = {0.f, 0.f, 0.f, 0.f};
#pragma unroll 8
    for (int j = 0; j < 128; ++j) {
      float mw = sCmp[j * 64 + lane];
      float4 a = S[j];
      o[0] = fmaf(a.x, mw, o[0]);
      o[1] = fmaf(a.y, mw, o[1]);
      o[2] = fmaf(a.z, mw, o[2]);
      o[3] = fmaf(a.w, mw, o[3]);
    }
    __builtin_amdgcn_wave_barrier();
#pragma unroll
    for (int i = 0; i < 4; ++i) {
      int nd = node0 + i;
      if (nd < n) mu[(size_t)nd * 64 + lane] = fmaxf(o[i], 0.f);
    }
  }
}

// ---------------- pooling (batch_ids sorted -> chunked partial sums) ----------------
__global__ __launch_bounds__(256) void k_pool(
    const float* __restrict__ mu, const int* __restrict__ batch,
    float* __restrict__ pool, int n) {
  int gw = (blockIdx.x * blockDim.x + threadIdx.x) >> 6;
  int lane = threadIdx.x & 63;
  int start = gw * 256;
  if (start >= n) return;
  int end = min(start + 256, n);
  int cur = batch[start];
  float acc = 0.f;
  for (int i = start; i < end; ++i) {
    int b = batch[i];
    if (b != cur) {
      atomicAdd(&pool[cur * 64 + lane], acc);
      acc = 0.f;
      cur = b;
    }
    acc += mu[(size_t)i * 64 + lane];
  }
  atomicAdd(&pool[cur * 64 + lane], acc);
}

__global__ void k_poolw6(const float* __restrict__ pool, const float* __restrict__ W6,
                         float* __restrict__ out) {
  int idx = blockIdx.x * blockDim.x + threadIdx.x;  // < 4096
  int g = idx >> 6, p = idx & 63;
  float s = 0.f;
  for (int k = 0; k < 64; ++k) s += pool[g * 64 + k] * W6[p * 64 + k];
  out[idx] = s;
}

// ---------------- head ----------------
__global__ __launch_bounds__(256) void k_final(
    const float* __restrict__ mu, const int* __restrict__ batch,
    const float* __restrict__ poolw6, const float* __restrict__ W7t,
    const float* __restrict__ W5, float* __restrict__ out, int n) {
  __shared__ float S[4][64];
  int tid = threadIdx.x, lane = tid & 63, w = tid >> 6;
  int node = blockIdx.x * 4 + w;
  if (node >= n) return;
  float mv = mu[(size_t)node * 64 + lane];
  S[w][lane] = mv;
  __builtin_amdgcn_wave_barrier();
  int g = batch[node];
  float t1 = fmaxf(poolw6[g * 64 + lane], 0.f);
  float acc = 0.f;
#pragma unroll 8
  for (int j = 0; j < 64; ++j) acc = fmaf(S[w][j], W7t[j * 64 + lane], acc);
  float t2 = fmaxf(acc, 0.f);
  float val = W5[lane] * t1 + W5[64 + lane] * t2;
  for (int off = 32; off > 0; off >>= 1) val += __shfl_down(val, off);
  if (lane == 0) out[node] = fmaxf(val, 0.f);
}

extern "C" void kernel_launch(void* const* d_in, const int* in_sizes, int n_in,
                              void* d_out, int out_size, void* d_ws, size_t ws_size,
                              hipStream_t stream) {
  const float* x = (const float*)d_in[0];
  const float* weight = (const float*)d_in[1];
  const int* ei = (const int*)d_in[2];
  const int* batch = (const int*)d_in[3];
  const float* W1 = (const float*)d_in[4];
  const float* W2 = (const float*)d_in[5];
  const float* W3 = (const float*)d_in[6];
  const float* W4 = (const float*)d_in[7];
  const float* Wc1 = (const float*)d_in[8];
  const float* Wc2 = (const float*)d_in[9];
  const float* Wcomp = (const float*)d_in[10];
  const float* W5 = (const float*)d_in[11];
  const float* W6 = (const float*)d_in[12];
  const float* W7 = (const float*)d_in[13];
  float* out = (float*)d_out;
  int N = in_sizes[0];
  int E = in_sizes[1];
  int T = in_sizes[4] / 64;

  int K = (N + RB - 1) / RB;            // buckets (<= 256 for N <= 128K)
  int cap = E / K + E / (4 * K) + 1024; // per-bucket capacity with >6-sigma margin

  char* ws = (char*)d_ws;
  size_t off = 0;
  auto alloc = [&](size_t bytes) {
    size_t o = off;
    off += (bytes + 255) & ~(size_t)255;
    return o;
  };
  // zeroed region
  size_t o_bcnt = alloc((size_t)2 * K * 4);
  size_t o_pool = alloc(4096 * 4);
  size_t zero_end = off;
  size_t o_beg_in = alloc((size_t)N * 4);
  size_t o_end_in = alloc((size_t)N * 4);
  size_t o_beg_out = alloc((size_t)N * 4);
  size_t o_end_out = alloc((size_t)N * 4);
  size_t o_sw_in = alloc((size_t)N * 4);
  size_t o_sw_out = alloc((size_t)N * 4);
  size_t o_col_in = alloc((size_t)K * cap * 4);
  size_t o_col_out = alloc((size_t)K * cap * 4);
  size_t o_mu = alloc((size_t)N * 64 * 4);
  size_t aggBytes = (size_t)N * 64 * 4;
  size_t bktBytes = (size_t)K * cap * 8;
  size_t big = aggBytes > bktBytes ? aggBytes : bktBytes;
  size_t o_agg_in = alloc(big);   // aliased: bkt_in during build
  size_t o_agg_out = alloc(big);  // aliased: bkt_out during build
  size_t o_c1 = alloc(4 * 64 * 4);
  size_t o_c3 = alloc(4 * 64 * 4);
  size_t o_Mt = alloc(4 * 4096 * 4);
  size_t o_Wc2t = alloc(4 * 4096 * 4);
  size_t o_WcompT = alloc(8192 * 4);
  size_t o_W7t = alloc(4096 * 4);
  size_t o_poolw6 = alloc(4096 * 4);
  (void)ws_size; (void)n_in; (void)out_size;

  hipMemsetAsync(ws, 0, zero_end, stream);

  dim3 gBin((E + BIN_C - 1) / BIN_C, 2);
  k_bin<<<gBin, 256, 0, stream>>>(ei, weight, (uint2*)(ws + o_agg_in),
                                  (uint2*)(ws + o_agg_out), (int*)(ws + o_bcnt),
                                  E, K, cap);
  dim3 gBkt(K, 2);
  k_bucket<<<gBkt, 256, 0, stream>>>((uint2*)(ws + o_agg_in), (uint2*)(ws + o_agg_out),
                                     (int*)(ws + o_bcnt),
                                     (int*)(ws + o_beg_in), (int*)(ws + o_end_in),
                                     (int*)(ws + o_beg_out), (int*)(ws + o_end_out),
                                     (float*)(ws + o_sw_in), (float*)(ws + o_sw_out),
                                     (int*)(ws + o_col_in), (int*)(ws + o_col_out),
                                     cap, N, K);
  k_wprep<<<T, 256, 0, stream>>>(W1, W2, W3, W4, Wc1, Wc2, Wcomp, W7,
                                 (float*)(ws + o_c1), (float*)(ws + o_c3),
                                 (float*)(ws + o_Mt), (float*)(ws + o_Wc2t),
                                 (float*)(ws + o_WcompT), (float*)(ws + o_W7t));

  int gN16 = (N + 15) / 16;
  int gN4 = (N + 3) / 4;
  int gNode = gN16 < 512 ? gN16 : 512;   // 2 blocks/CU resident exactly
  for (int t = 0; t < T; ++t) {
    if (t > 0)
      k_agg<<<gN4, 256, 0, stream>>>((int*)(ws + o_beg_in), (int*)(ws + o_end_in),
                                     (int*)(ws + o_col_in),
                                     (int*)(ws + o_beg_out), (int*)(ws + o_end_out),
                                     (int*)(ws + o_col_out),
                                     (float*)(ws + o_mu), (float*)(ws + o_agg_in),
                                     (float*)(ws + o_agg_out), N);
    k_node<<<gNode, 256, 0, stream>>>(x, (float*)(ws + o_sw_in), (float*)(ws + o_sw_out),
                                      (float*)(ws + o_agg_in), (float*)(ws + o_agg_out),
                                      (float*)(ws + o_c1), (float*)(ws + o_c3),
                                      (float*)(ws + o_Mt), (float*)(ws + o_Wc2t),
                                      (float*)(ws + o_WcompT), (float*)(ws + o_mu),
                                      N, t, t > 0 ? 1 : 0);
  }
  int gPool = ((N + 255) / 256 + 3) / 4;
  k_pool<<<gPool, 256, 0, stream>>>((float*)(ws + o_mu), batch, (float*)(ws + o_pool), N);
  k_poolw6<<<16, 256, 0, stream>>>((float*)(ws + o_pool), W6, (float*)(ws + o_poolw6));
  k_final<<<gN4, 256, 0, stream>>>((float*)(ws + o_mu), batch, (float*)(ws + o_poolw6),
                                   (float*)(ws + o_W7t), W5, out, N);
}